// Round 1
// baseline (428.708 us; speedup 1.0000x reference)
//
#include <hip/hip_runtime.h>
#include <hip/hip_bf16.h>

#define L_ATT 2304
#define TK 576
#define SCALE_ATT 0.35355339059327373f

// ---------------------------------------------------------------------------
// 1x1 conv as tiled GEMM: out[n,oc,l] = bias[oc] + sum_ic w[oc,ic] * x[n,ic,l]
// grid: (L/64, Cout/64, N); block 256. 64x64 tile, BK=16, 4x4 per thread.
// ---------------------------------------------------------------------------
__global__ __launch_bounds__(256) void conv1x1_kernel(
    const float* __restrict__ x, const float* __restrict__ w,
    const float* __restrict__ bias, float* __restrict__ out,
    int Cin, int Cout, int L)
{
    const int l0  = blockIdx.x * 64;
    const int oc0 = blockIdx.y * 64;
    const int n   = blockIdx.z;
    const int tid = threadIdx.x;
    const int tx  = tid & 15;   // -> l
    const int ty  = tid >> 4;   // -> oc

    __shared__ float sW[64][17];  // [oc'][k], padded
    __shared__ float sX[16][64];  // [k][l']

    float acc[4][4];
#pragma unroll
    for (int i = 0; i < 4; ++i)
#pragma unroll
        for (int j = 0; j < 4; ++j) acc[i][j] = 0.f;

    const float* xn = x + (size_t)n * Cin * L;

    for (int k0 = 0; k0 < Cin; k0 += 16) {
        __syncthreads();
        {   // load W tile: 64 oc x 16 k
            int ocl = tid >> 2;
            int kk  = (tid & 3) * 4;
            const float4 wv = *(const float4*)(w + (size_t)(oc0 + ocl) * Cin + k0 + kk);
            sW[ocl][kk + 0] = wv.x; sW[ocl][kk + 1] = wv.y;
            sW[ocl][kk + 2] = wv.z; sW[ocl][kk + 3] = wv.w;
        }
        {   // load X tile: 16 k x 64 l
            int kr = tid >> 4;
            int ll = (tid & 15) * 4;
            const float4 xv = *(const float4*)(xn + (size_t)(k0 + kr) * L + l0 + ll);
            *(float4*)&sX[kr][ll] = xv;
        }
        __syncthreads();
#pragma unroll
        for (int k = 0; k < 16; ++k) {
            float a[4], b[4];
#pragma unroll
            for (int i = 0; i < 4; ++i) a[i] = sW[ty + 16 * i][k];
#pragma unroll
            for (int j = 0; j < 4; ++j) b[j] = sX[k][tx + 16 * j];
#pragma unroll
            for (int i = 0; i < 4; ++i)
#pragma unroll
                for (int j = 0; j < 4; ++j) acc[i][j] += a[i] * b[j];
        }
    }

#pragma unroll
    for (int i = 0; i < 4; ++i) {
        int oc = oc0 + ty + 16 * i;
        float bb = bias[oc];
#pragma unroll
        for (int j = 0; j < 4; ++j) {
            out[((size_t)n * Cout + oc) * L + l0 + tx + 16 * j] = acc[i][j] + bb;
        }
    }
}

// ---------------------------------------------------------------------------
// Flash attention, D=8, one query per thread. qkv layout (N,192,L):
// q row = h*24+d, k row = h*24+8+d, v row = h*24+16+d.
// grid: (L/128, NH=8, N=4); block 128. No max-subtraction (logits |x|<~10).
// out: (N,64,L) with channel = h*8+d.
// ---------------------------------------------------------------------------
__global__ __launch_bounds__(128) void attn_kernel(
    const float* __restrict__ qkv, float* __restrict__ out)
{
    const int n = blockIdx.z, h = blockIdx.y;
    const int tid = threadIdx.x;
    const int qi = blockIdx.x * 128 + tid;
    const float* base = qkv + ((size_t)n * 192 + h * 24) * L_ATT;

    float q[8];
#pragma unroll
    for (int d = 0; d < 8; ++d) q[d] = base[d * L_ATT + qi] * SCALE_ATT;

    __shared__ float ks[TK * 8];   // j-major [j][d]
    __shared__ float vs[TK * 8];

    float acc[8] = {0.f, 0.f, 0.f, 0.f, 0.f, 0.f, 0.f, 0.f};
    float lsum = 0.f;

    for (int kt = 0; kt < L_ATT; kt += TK) {
        __syncthreads();
#pragma unroll
        for (int d = 0; d < 8; ++d) {
            const float* kp = base + (size_t)(8 + d) * L_ATT + kt;
            const float* vp = base + (size_t)(16 + d) * L_ATT + kt;
            for (int j = tid; j < TK; j += 128) {
                ks[j * 8 + d] = kp[j];
                vs[j * 8 + d] = vp[j];
            }
        }
        __syncthreads();
        const float4* k4 = (const float4*)ks;
        const float4* v4 = (const float4*)vs;
#pragma unroll 4
        for (int j = 0; j < TK; ++j) {
            float4 ka = k4[2 * j], kb = k4[2 * j + 1];
            float logit = q[0] * ka.x + q[1] * ka.y + q[2] * ka.z + q[3] * ka.w
                        + q[4] * kb.x + q[5] * kb.y + q[6] * kb.z + q[7] * kb.w;
            float e = __expf(logit);
            float4 va = v4[2 * j], vb = v4[2 * j + 1];
            lsum += e;
            acc[0] += e * va.x; acc[1] += e * va.y; acc[2] += e * va.z; acc[3] += e * va.w;
            acc[4] += e * vb.x; acc[5] += e * vb.y; acc[6] += e * vb.z; acc[7] += e * vb.w;
        }
    }

    float inv = 1.0f / lsum;
#pragma unroll
    for (int d = 0; d < 8; ++d)
        out[((size_t)n * 64 + h * 8 + d) * L_ATT + qi] = acc[d] * inv;
}

// ---------------------------------------------------------------------------
// 3x3 SAME pos-conv on v (64->64 ch) fused with "+= attention output":
// t[n,oc,l] = t[n,oc,l] + pos_b[oc] + sum_ic sum_{3x3} pos_w * v
// v channel ic lives at qkv row (ic>>3)*24 + 16 + (ic&7).
// grid: (64, N); block 256; 9 pixels per thread (2304 = 9*256).
// ---------------------------------------------------------------------------
__global__ __launch_bounds__(256) void posconv_add_kernel(
    const float* __restrict__ qkv, const float* __restrict__ pw,
    const float* __restrict__ pb, float* __restrict__ t)
{
    const int oc = blockIdx.x, n = blockIdx.y;
    const int tid = threadIdx.x;

    __shared__ float sp[50 * 50];   // zero-padded plane
    for (int p = tid; p < 2500; p += 256) sp[p] = 0.f;

    int c9[9];
#pragma unroll
    for (int r = 0; r < 9; ++r) {
        int p = tid + 256 * r;
        int y = p / 48, x = p - y * 48;
        c9[r] = (y + 1) * 50 + (x + 1);
    }

    float acc[9];
#pragma unroll
    for (int r = 0; r < 9; ++r) acc[r] = 0.f;

    for (int ic = 0; ic < 64; ++ic) {
        __syncthreads();   // also covers the zero-init on first iteration
        const float* vp = qkv + ((size_t)n * 192 + (ic >> 3) * 24 + 16 + (ic & 7)) * L_ATT;
#pragma unroll
        for (int r = 0; r < 9; ++r) sp[c9[r]] = vp[tid + 256 * r];
        __syncthreads();
        float w9[9];
#pragma unroll
        for (int qq = 0; qq < 9; ++qq) w9[qq] = pw[((size_t)oc * 64 + ic) * 9 + qq];
#pragma unroll
        for (int r = 0; r < 9; ++r) {
            int c = c9[r];
            float s = 0.f;
#pragma unroll
            for (int dy = 0; dy < 3; ++dy)
#pragma unroll
                for (int dx = 0; dx < 3; ++dx)
                    s += w9[dy * 3 + dx] * sp[c + (dy - 1) * 50 + (dx - 1)];
            acc[r] += s;
        }
    }

    float bb = pb[oc];
    float* tp = t + ((size_t)n * 64 + oc) * L_ATT;
#pragma unroll
    for (int r = 0; r < 9; ++r) {
        int p = tid + 256 * r;
        tp[p] = tp[p] + acc[r] + bb;
    }
}

// ---------------------------------------------------------------------------
extern "C" void kernel_launch(void* const* d_in, const int* in_sizes, int n_in,
                              void* d_out, int out_size, void* d_ws, size_t ws_size,
                              hipStream_t stream)
{
    const float* x      = (const float*)d_in[0];
    const float* qkv_w  = (const float*)d_in[1];
    const float* qkv_b  = (const float*)d_in[2];
    const float* pos_w  = (const float*)d_in[3];
    const float* pos_b  = (const float*)d_in[4];
    const float* res_w  = (const float*)d_in[5];
    const float* res_b  = (const float*)d_in[6];
    float* out = (float*)d_out;

    float* qkvb = (float*)d_ws;                       // (4,192,2304) = 7.08 MB
    float* tb   = qkvb + (size_t)4 * 192 * L_ATT;     // (4,64,2304)  = 2.36 MB

    // 1) qkv = 1x1 conv (Cin=512 -> Cout=192)
    conv1x1_kernel<<<dim3(36, 3, 4), 256, 0, stream>>>(x, qkv_w, qkv_b, qkvb, 512, 192, L_ATT);
    // 2) attention -> tb (N,64,L)
    attn_kernel<<<dim3(18, 8, 4), 128, 0, stream>>>(qkvb, tb);
    // 3) tb += 3x3 pos-conv(v)
    posconv_add_kernel<<<dim3(64, 4), 256, 0, stream>>>(qkvb, pos_w, pos_b, tb);
    // 4) out = 1x1 conv (Cin=64 -> Cout=512)
    conv1x1_kernel<<<dim3(36, 8, 4), 256, 0, stream>>>(tb, res_w, res_b, out, 64, 512, L_ATT);
}

// Round 2
// 395.956 us; speedup vs baseline: 1.0827x; 1.0827x over previous
//
#include <hip/hip_runtime.h>
#include <hip/hip_bf16.h>

#define L_ATT 2304
#define SCALE_ATT 0.35355339059327373f
#define AT_STRIDE 68   // 17 float4s: 16B-aligned rows, <=2-way bank conflicts

// ---------------------------------------------------------------------------
// 1x1 conv as tiled GEMM: out[n,oc,l] = bias[oc] + sum_ic w[oc,ic] * x[n,ic,l]
// 64x64 tile, BK=16, 4x4 per thread; W staged transposed [k][oc] so both
// LDS operand reads are float4 (2 x ds_read_b128 per k-step per thread).
// ---------------------------------------------------------------------------
__global__ __launch_bounds__(256) void conv1x1_kernel(
    const float* __restrict__ x, const float* __restrict__ w,
    const float* __restrict__ bias, float* __restrict__ out,
    int Cin, int Cout, int L)
{
    const int l0  = blockIdx.x * 64;
    const int oc0 = blockIdx.y * 64;
    const int n   = blockIdx.z;
    const int tid = threadIdx.x;
    const int tx  = tid & 15;   // -> l group
    const int ty  = tid >> 4;   // -> oc group

    __shared__ float sW[16][64];  // [k][oc]
    __shared__ float sX[16][64];  // [k][l]

    float acc[4][4] = {};

    const float* xn = x + (size_t)n * Cin * L;
    const int wo = tid >> 2;        // oc' 0..63
    const int wk = (tid & 3) * 4;   // k'  0,4,8,12
    const int xr = tid >> 4;        // k row 0..15
    const int xc = (tid & 15) * 4;  // col

    for (int k0 = 0; k0 < Cin; k0 += 16) {
        __syncthreads();
        {   // W tile (transposed store)
            float4 wv = *(const float4*)(w + (size_t)(oc0 + wo) * Cin + k0 + wk);
            sW[wk + 0][wo] = wv.x; sW[wk + 1][wo] = wv.y;
            sW[wk + 2][wo] = wv.z; sW[wk + 3][wo] = wv.w;
        }
        {   // X tile
            *(float4*)&sX[xr][xc] = *(const float4*)(xn + (size_t)(k0 + xr) * L + l0 + xc);
        }
        __syncthreads();
#pragma unroll
        for (int k = 0; k < 16; ++k) {
            float4 a4 = *(float4*)&sW[k][ty * 4];
            float4 b4 = *(float4*)&sX[k][tx * 4];
            float a[4] = {a4.x, a4.y, a4.z, a4.w};
            float b[4] = {b4.x, b4.y, b4.z, b4.w};
#pragma unroll
            for (int i = 0; i < 4; ++i)
#pragma unroll
                for (int j = 0; j < 4; ++j) acc[i][j] += a[i] * b[j];
        }
    }

#pragma unroll
    for (int i = 0; i < 4; ++i) {
        int oc = oc0 + ty * 4 + i;
        float bb = bias[oc];
        float4 o4 = {acc[i][0] + bb, acc[i][1] + bb, acc[i][2] + bb, acc[i][3] + bb};
        *(float4*)(out + ((size_t)n * Cout + oc) * L + l0 + tx * 4) = o4;
    }
}

// ---------------------------------------------------------------------------
// Flash attention, D=8. Block = 256 threads = 16 q-groups(ty) x 16 k-groups(tx).
// Thread: 4 queries x 4 keys logits, acc[4 q][8 d]. Q in registers; K/V staged
// [d][key] (stride 68). Epilogue: shfl_xor reduce over the 16 tx lanes.
// grid: (L/64, NH=8, N=4).
// ---------------------------------------------------------------------------
__global__ __launch_bounds__(256) void attn_kernel(
    const float* __restrict__ qkv, float* __restrict__ out)
{
    const int n = blockIdx.z, h = blockIdx.y;
    const int q0 = blockIdx.x * 64;
    const int tid = threadIdx.x;
    const int tx = tid & 15;
    const int ty = tid >> 4;

    __shared__ float qs[8 * AT_STRIDE];
    __shared__ float ks[8 * AT_STRIDE];
    __shared__ float vs[8 * AT_STRIDE];
    __shared__ float Os[64 * 8];

    const float* base = qkv + ((size_t)n * 192 + h * 24) * L_ATT;

    // stage Q tile (scaled)
    if (tid < 128) {
        int d = tid >> 4, c = (tid & 15) * 4;
        float4 qv = *(const float4*)(base + (size_t)d * L_ATT + q0 + c);
        qv.x *= SCALE_ATT; qv.y *= SCALE_ATT; qv.z *= SCALE_ATT; qv.w *= SCALE_ATT;
        *(float4*)&qs[d * AT_STRIDE + c] = qv;
    }
    __syncthreads();

    float a[4][8];
#pragma unroll
    for (int d = 0; d < 8; ++d) {
        float4 a4 = *(float4*)&qs[d * AT_STRIDE + ty * 4];
        a[0][d] = a4.x; a[1][d] = a4.y; a[2][d] = a4.z; a[3][d] = a4.w;
    }

    float acc[4][8] = {};
    float lsum[4] = {};

    // K/V staging role for this thread (one float4 per tile)
    const int kvsel = tid >> 7;           // 0 = K, 1 = V
    const int sd = (tid >> 4) & 7;
    const int sc = (tid & 15) * 4;
    const float* src = base + (size_t)(8 + 8 * kvsel + sd) * L_ATT + sc;
    float* dst = (kvsel ? vs : ks) + sd * AT_STRIDE + sc;

    for (int kt = 0; kt < L_ATT; kt += 64) {
        __syncthreads();
        *(float4*)dst = *(const float4*)(src + kt);
        __syncthreads();

        float e[4][4] = {};
#pragma unroll
        for (int d = 0; d < 8; ++d) {
            float4 k4 = *(float4*)&ks[d * AT_STRIDE + tx * 4];
#pragma unroll
            for (int i = 0; i < 4; ++i) {
                e[i][0] += a[i][d] * k4.x;
                e[i][1] += a[i][d] * k4.y;
                e[i][2] += a[i][d] * k4.z;
                e[i][3] += a[i][d] * k4.w;
            }
        }
#pragma unroll
        for (int i = 0; i < 4; ++i)
#pragma unroll
            for (int j = 0; j < 4; ++j) {
                e[i][j] = __expf(e[i][j]);
                lsum[i] += e[i][j];
            }
#pragma unroll
        for (int d = 0; d < 8; ++d) {
            float4 v4 = *(float4*)&vs[d * AT_STRIDE + tx * 4];
#pragma unroll
            for (int i = 0; i < 4; ++i)
                acc[i][d] += e[i][0] * v4.x + e[i][1] * v4.y
                           + e[i][2] * v4.z + e[i][3] * v4.w;
        }
    }

    // reduce over the 16 tx lanes (same wave: masks 1,2,4,8)
#pragma unroll
    for (int m = 1; m < 16; m <<= 1) {
#pragma unroll
        for (int i = 0; i < 4; ++i) {
            lsum[i] += __shfl_xor(lsum[i], m, 64);
#pragma unroll
            for (int d = 0; d < 8; ++d)
                acc[i][d] += __shfl_xor(acc[i][d], m, 64);
        }
    }
    if (tx == 0) {
#pragma unroll
        for (int i = 0; i < 4; ++i) {
            float inv = 1.0f / lsum[i];
#pragma unroll
            for (int d = 0; d < 8; ++d)
                Os[(ty * 4 + i) * 8 + d] = acc[i][d] * inv;
        }
    }
    __syncthreads();
    {   // cooperative coalesced store: 512 floats
        int d = tid >> 5, qq = (tid & 31) * 2;
        float2 o2 = { Os[qq * 8 + d], Os[(qq + 1) * 8 + d] };
        *(float2*)(out + ((size_t)n * 64 + h * 8 + d) * L_ATT + q0 + qq) = o2;
    }
}

// ---------------------------------------------------------------------------
// 3x3 SAME pos-conv on v (64->64 ch) fused with "+= attention output".
// Block 128: 2 oc, 16-row band, 6 consecutive px per thread (float2 window
// reads from padded 18x52 LDS plane). grid: (32 oc-pairs, 3 bands, 4 n).
// ---------------------------------------------------------------------------
__global__ __launch_bounds__(128) void posconv_add_kernel(
    const float* __restrict__ qkv, const float* __restrict__ pw,
    const float* __restrict__ pb, float* __restrict__ t)
{
    const int oc0 = blockIdx.x * 2;
    const int r0  = blockIdx.y * 16;
    const int n   = blockIdx.z;
    const int tid = threadIdx.x;

    __shared__ float sp[18 * 52];   // rows r0-1..r0+16, col c = x+1; borders stay 0
    for (int p = tid; p < 18 * 52; p += 128) sp[p] = 0.f;

    int srow[7], sx[7]; bool svalid[7];
#pragma unroll
    for (int s = 0; s < 7; ++s) {
        int p = tid + 128 * s;
        int row = p / 48, xx = p - row * 48;
        srow[s] = row; sx[s] = xx;
        int y = r0 - 1 + row;
        svalid[s] = (p < 864) && (y >= 0) && (y < 48);
    }

    const int rr = tid >> 3;          // row in band 0..15
    const int cx = (tid & 7) * 6;     // first px col
    const int wbase = rr * 52 + cx;   // window: rows rr..rr+2, 8 cols

    float acc[2][6] = {};

    for (int ic = 0; ic < 64; ++ic) {
        const float* vp = qkv + ((size_t)n * 192 + (ic >> 3) * 24 + 16 + (ic & 7)) * L_ATT;
        __syncthreads();
#pragma unroll
        for (int s = 0; s < 7; ++s)
            if (svalid[s])
                sp[srow[s] * 52 + sx[s] + 1] = vp[(r0 - 1 + srow[s]) * 48 + sx[s]];
        __syncthreads();

        float w2[2][9];
#pragma unroll
        for (int i2 = 0; i2 < 2; ++i2)
#pragma unroll
            for (int q = 0; q < 9; ++q)
                w2[i2][q] = pw[((size_t)(oc0 + i2) * 64 + ic) * 9 + q];

#pragma unroll
        for (int r = 0; r < 3; ++r) {
            float win[8];
#pragma unroll
            for (int c2 = 0; c2 < 4; ++c2) {
                float2 f2 = *(float2*)&sp[wbase + r * 52 + c2 * 2];
                win[c2 * 2] = f2.x; win[c2 * 2 + 1] = f2.y;
            }
#pragma unroll
            for (int i2 = 0; i2 < 2; ++i2)
#pragma unroll
                for (int c = 0; c < 6; ++c)
                    acc[i2][c] += w2[i2][r * 3 + 0] * win[c]
                                + w2[i2][r * 3 + 1] * win[c + 1]
                                + w2[i2][r * 3 + 2] * win[c + 2];
        }
    }

    const int px = (r0 + rr) * 48 + cx;
#pragma unroll
    for (int i2 = 0; i2 < 2; ++i2) {
        float bb = pb[oc0 + i2];
        float* tp = t + ((size_t)n * 64 + oc0 + i2) * L_ATT + px;
#pragma unroll
        for (int c = 0; c < 6; ++c) tp[c] += acc[i2][c] + bb;
    }
}

// ---------------------------------------------------------------------------
extern "C" void kernel_launch(void* const* d_in, const int* in_sizes, int n_in,
                              void* d_out, int out_size, void* d_ws, size_t ws_size,
                              hipStream_t stream)
{
    const float* x      = (const float*)d_in[0];
    const float* qkv_w  = (const float*)d_in[1];
    const float* qkv_b  = (const float*)d_in[2];
    const float* pos_w  = (const float*)d_in[3];
    const float* pos_b  = (const float*)d_in[4];
    const float* res_w  = (const float*)d_in[5];
    const float* res_b  = (const float*)d_in[6];
    float* out = (float*)d_out;

    float* qkvb = (float*)d_ws;                       // (4,192,2304)
    float* tb   = qkvb + (size_t)4 * 192 * L_ATT;     // (4,64,2304)

    // 1) qkv = 1x1 conv (512 -> 192)
    conv1x1_kernel<<<dim3(36, 3, 4), 256, 0, stream>>>(x, qkv_w, qkv_b, qkvb, 512, 192, L_ATT);
    // 2) attention -> tb (N,64,L)
    attn_kernel<<<dim3(36, 8, 4), 256, 0, stream>>>(qkvb, tb);
    // 3) tb += 3x3 pos-conv(v)
    posconv_add_kernel<<<dim3(32, 3, 4), 128, 0, stream>>>(qkvb, pos_w, pos_b, tb);
    // 4) out = 1x1 conv (64 -> 512)
    conv1x1_kernel<<<dim3(36, 8, 4), 256, 0, stream>>>(tb, res_w, res_b, out, 64, 512, L_ATT);
}

// Round 3
// 246.911 us; speedup vs baseline: 1.7363x; 1.6036x over previous
//
#include <hip/hip_runtime.h>

#define L_ATT 2304
#define SCALE_ATT 0.35355339059327373f

using bh8 = __attribute__((ext_vector_type(8))) short;  // 8 bf16 (4 VGPRs)
using f4  = __attribute__((ext_vector_type(4))) float;  // 4 fp32 acc

__device__ inline short f2b(float f) {
    union { float f; unsigned u; } c; c.f = f;
    unsigned r = (c.u + 0x7FFFu + ((c.u >> 16) & 1u)) >> 16;
    return (short)r;
}
__device__ inline float b2f(short s) {
    union { unsigned u; float f; } c;
    c.u = ((unsigned)(unsigned short)s) << 16;
    return c.f;
}

// ---------------------------------------------------------------------------
// Convert qkv_w (192x512) and res_w (512x64) fp32 -> bf16 (natural layout).
// ---------------------------------------------------------------------------
__global__ __launch_bounds__(256) void wcvt_kernel(
    const float* __restrict__ qkv_w, const float* __restrict__ res_w,
    short* __restrict__ wqb, short* __restrict__ reswb)
{
    int j = blockIdx.x * 256 + threadIdx.x;   // 32768 threads, one float4 each
    const float4* src; short* dst; int idx;
    if (j < 24576) { src = (const float4*)qkv_w; dst = wqb;   idx = j; }
    else           { src = (const float4*)res_w; dst = reswb; idx = j - 24576; }
    float4 v = src[idx];
    short4 o = { f2b(v.x), f2b(v.y), f2b(v.z), f2b(v.w) };
    *(short4*)(dst + (size_t)idx * 4) = o;
}

// ---------------------------------------------------------------------------
// x [n][512][2304] fp32 -> xt [n][2304][512] bf16 (LDS tile transpose).
// grid (36, 8, 4)
// ---------------------------------------------------------------------------
__global__ __launch_bounds__(256) void xt_kernel(
    const float* __restrict__ x, short* __restrict__ xt)
{
    const int l0 = blockIdx.x * 64, k0 = blockIdx.y * 64, n = blockIdx.z;
    __shared__ float s[64][68];
    const int tr = threadIdx.x >> 4, tc4 = (threadIdx.x & 15) * 4;
    const float* xp = x + ((size_t)n * 512 + k0) * L_ATT + l0;
#pragma unroll
    for (int r = 0; r < 4; ++r)
        *(float4*)&s[tr + r * 16][tc4] =
            *(const float4*)(xp + (size_t)(tr + r * 16) * L_ATT + tc4);
    __syncthreads();
    short* op = xt + ((size_t)n * L_ATT + l0) * 512 + k0;
#pragma unroll
    for (int r = 0; r < 4; ++r) {
        int l = tr + r * 16;
        short4 o = { f2b(s[tc4 + 0][l]), f2b(s[tc4 + 1][l]),
                     f2b(s[tc4 + 2][l]), f2b(s[tc4 + 3][l]) };
        *(short4*)(op + (size_t)l * 512 + tc4) = o;
    }
}

// ---------------------------------------------------------------------------
// qkv 1x1 conv as MFMA GEMM, fragments loaded straight from global.
// D[oc][l] = sum_k W[oc][k] X[k][l];  A = wqb[oc][k], B = xt[l][k].
// Epilogue scatters: q (x SCALE) and k -> qkt[n][h][l][16]; v -> vt[n][h][d][l].
// grid (36, 3, 4), block 256 (4 waves x 16-oc strip).
// ---------------------------------------------------------------------------
__global__ __launch_bounds__(256) void qkv_kernel(
    const short* __restrict__ xt, const short* __restrict__ wqb,
    const float* __restrict__ qkv_b, short* __restrict__ qkt,
    short* __restrict__ vt)
{
    const int l0 = blockIdx.x * 64, oc0 = blockIdx.y * 64, n = blockIdx.z;
    const int lane = threadIdx.x & 63, wave = threadIdx.x >> 6;
    const int col = lane & 15, quad = lane >> 4;
    const int ocb = oc0 + wave * 16;

    f4 acc[4];
#pragma unroll
    for (int nt = 0; nt < 4; ++nt) acc[nt] = (f4){0.f, 0.f, 0.f, 0.f};

    const short* arow = wqb + (size_t)(ocb + col) * 512 + quad * 8;
    const short* brow = xt + ((size_t)n * L_ATT + l0 + col) * 512 + quad * 8;

#pragma unroll 4
    for (int k0 = 0; k0 < 512; k0 += 32) {
        bh8 af = *(const bh8*)(arow + k0);
        bh8 b0 = *(const bh8*)(brow + k0);
        bh8 b1 = *(const bh8*)(brow + (size_t)16 * 512 + k0);
        bh8 b2 = *(const bh8*)(brow + (size_t)32 * 512 + k0);
        bh8 b3 = *(const bh8*)(brow + (size_t)48 * 512 + k0);
        acc[0] = __builtin_amdgcn_mfma_f32_16x16x32_bf16(af, b0, acc[0], 0, 0, 0);
        acc[1] = __builtin_amdgcn_mfma_f32_16x16x32_bf16(af, b1, acc[1], 0, 0, 0);
        acc[2] = __builtin_amdgcn_mfma_f32_16x16x32_bf16(af, b2, acc[2], 0, 0, 0);
        acc[3] = __builtin_amdgcn_mfma_f32_16x16x32_bf16(af, b3, acc[3], 0, 0, 0);
    }

#pragma unroll
    for (int nt = 0; nt < 4; ++nt) {
        int l = l0 + nt * 16 + col;
#pragma unroll
        for (int reg = 0; reg < 4; ++reg) {
            int oc = ocb + quad * 4 + reg;
            float v = acc[nt][reg] + qkv_b[oc];
            int h = oc / 24;
            int r = oc - h * 24;
            if (r < 16) {
                float sv = (r < 8) ? v * SCALE_ATT : v;
                qkt[(((size_t)(n * 8 + h)) * L_ATT + l) * 16 + r] = f2b(sv);
            } else {
                vt[(((size_t)(n * 8 + h)) * 8 + (r - 16)) * L_ATT + l] = f2b(v);
            }
        }
    }
}

// ---------------------------------------------------------------------------
// Flash attention via MFMA. Wave owns 16 queries; K padded 8->32 (zero quads).
// S = Q K^T (4 MFMA / 64-key tile), exp fp32, P -> per-wave LDS [q][key],
// O += P V^T (2 MFMA, K=32 each); B column 8 = ones => lsum for free.
// No __syncthreads at all. grid (36, 8, 4), block 256.
// ---------------------------------------------------------------------------
__global__ __launch_bounds__(256) void attn_kernel(
    const short* __restrict__ qkt, const short* __restrict__ vt,
    float* __restrict__ t32)
{
    const int q0 = blockIdx.x * 64, h = blockIdx.y, n = blockIdx.z;
    const int lane = threadIdx.x & 63, wave = threadIdx.x >> 6;
    const int col = lane & 15, quad = lane >> 4;

    __shared__ short pbuf[4][16][80];

    const short* qk = qkt + ((size_t)(n * 8 + h)) * L_ATT * 16;
    const short* vb = vt + ((size_t)(n * 8 + h)) * 8 * L_ATT;

    bh8 qf = {0, 0, 0, 0, 0, 0, 0, 0};
    if (quad == 0)
        qf = *(const bh8*)(qk + ((size_t)(q0 + wave * 16 + col)) * 16);

    bh8 onef;
#pragma unroll
    for (int j = 0; j < 8; ++j) onef[j] = (short)0x3F80;  // bf16 1.0

    f4 oacc = (f4){0.f, 0.f, 0.f, 0.f};
    short (*pbw)[80] = pbuf[wave];

    for (int kt = 0; kt < L_ATT; kt += 64) {
        f4 s[4];
#pragma unroll
        for (int nt = 0; nt < 4; ++nt) {
            bh8 kf = {0, 0, 0, 0, 0, 0, 0, 0};
            if (quad == 0)
                kf = *(const bh8*)(qk + ((size_t)(kt + nt * 16 + col)) * 16 + 8);
            f4 z = (f4){0.f, 0.f, 0.f, 0.f};
            s[nt] = __builtin_amdgcn_mfma_f32_16x16x32_bf16(qf, kf, z, 0, 0, 0);
        }
#pragma unroll
        for (int nt = 0; nt < 4; ++nt)
#pragma unroll
            for (int reg = 0; reg < 4; ++reg)
                pbw[quad * 4 + reg][nt * 16 + col] = f2b(__expf(s[nt][reg]));
        // compiler inserts lgkmcnt wait: same-wave LDS RAW
#pragma unroll
        for (int ks = 0; ks < 2; ++ks) {
            bh8 pf = *(const bh8*)&pbw[col][ks * 32 + quad * 8];
            bh8 vf = {0, 0, 0, 0, 0, 0, 0, 0};
            if (col < 8)
                vf = *(const bh8*)(vb + (size_t)col * L_ATT + kt + ks * 32 + quad * 8);
            else if (col == 8)
                vf = onef;
            oacc = __builtin_amdgcn_mfma_f32_16x16x32_bf16(pf, vf, oacc, 0, 0, 0);
        }
    }

    // lsum lives in column 8 of O; broadcast within the 16-lane group.
    float outv[4];
#pragma unroll
    for (int reg = 0; reg < 4; ++reg) {
        float ls = __shfl(oacc[reg], (lane & 48) | 8, 64);
        outv[reg] = oacc[reg] / ls;
    }
    if (col < 8) {
#pragma unroll
        for (int reg = 0; reg < 4; ++reg) {
            int l = q0 + wave * 16 + quad * 4 + reg;
            t32[((size_t)n * L_ATT + l) * 64 + h * 8 + col] = outv[reg];
        }
    }
}

// ---------------------------------------------------------------------------
// 3x3 SAME pos-conv on v (from vt planes, bf16) + t32 + bias -> tbh (bf16).
// Block 128: 2 oc, 8-row band, 3 px/thread; 4 ic planes staged per barrier.
// grid (32, 6, 4).
// ---------------------------------------------------------------------------
__global__ __launch_bounds__(128) void posconv_kernel(
    const short* __restrict__ vt, const float* __restrict__ pw,
    const float* __restrict__ pbias, const float* __restrict__ t32,
    short* __restrict__ tbh)
{
    const int oc0 = blockIdx.x * 2;
    const int r0  = blockIdx.y * 8;
    const int n   = blockIdx.z;
    const int tid = threadIdx.x;

    __shared__ float sp[4][10][52];
    __shared__ float sw[72];

    for (int p = tid; p < 4 * 10 * 52; p += 128) ((float*)sp)[p] = 0.f;

    const int rr = tid >> 4;          // 0..7
    const int cx = (tid & 15) * 3;    // 0..45

    float acc[2][3] = {};

    for (int icb = 0; icb < 16; ++icb) {
        __syncthreads();
        if (tid < 72) {
            int oc = tid / 36, rem = tid - oc * 36, ic = rem / 9, q = rem - ic * 9;
            sw[tid] = pw[((size_t)(oc0 + oc) * 64 + icb * 4 + ic) * 9 + q];
        }
#pragma unroll
        for (int j = 0; j < 15; ++j) {
            int e = tid + 128 * j;
            int pl = e / 480;
            int rem = e - pl * 480;
            int row = rem / 48;
            int xx  = rem - row * 48;
            int ic = icb * 4 + pl;
            int y = r0 - 1 + row;
            float val = 0.f;
            if (y >= 0 && y < 48)
                val = b2f(vt[(((size_t)(n * 8) + (ic >> 3)) * 8 + (ic & 7)) * L_ATT
                             + y * 48 + xx]);
            sp[pl][row][xx + 1] = val;
        }
        __syncthreads();
#pragma unroll
        for (int pl = 0; pl < 4; ++pl) {
            float win[3][5];
#pragma unroll
            for (int r = 0; r < 3; ++r)
#pragma unroll
                for (int c = 0; c < 5; ++c)
                    win[r][c] = sp[pl][rr + r][cx + c];
#pragma unroll
            for (int o = 0; o < 2; ++o) {
                const float* w9 = &sw[o * 36 + pl * 9];
#pragma unroll
                for (int r = 0; r < 3; ++r)
#pragma unroll
                    for (int c = 0; c < 3; ++c) {
                        float wv = w9[r * 3 + c];
                        acc[o][0] += wv * win[r][c];
                        acc[o][1] += wv * win[r][c + 1];
                        acc[o][2] += wv * win[r][c + 2];
                    }
            }
        }
    }

#pragma unroll
    for (int o = 0; o < 2; ++o) {
        int ch = oc0 + o;
        float bb = pbias[ch];
#pragma unroll
        for (int c = 0; c < 3; ++c) {
            int l = (r0 + rr) * 48 + cx + c;
            size_t idx = ((size_t)n * L_ATT + l) * 64 + ch;
            tbh[idx] = f2b(t32[idx] + acc[o][c] + bb);
        }
    }
}

// ---------------------------------------------------------------------------
// res 1x1 conv: out[n][oc][l] = res_b[oc] + sum_ch W[oc][ch] T[ch][l]. K=64.
// A = reswb[oc][ch], B = tbh[l][ch]; fragments direct from global.
// grid (36, 8, 4), block 256.
// ---------------------------------------------------------------------------
__global__ __launch_bounds__(256) void res_kernel(
    const short* __restrict__ tbh, const short* __restrict__ reswb,
    const float* __restrict__ res_b, float* __restrict__ out)
{
    const int l0 = blockIdx.x * 64, oc0 = blockIdx.y * 64, n = blockIdx.z;
    const int lane = threadIdx.x & 63, wave = threadIdx.x >> 6;
    const int col = lane & 15, quad = lane >> 4;
    const int ocb = oc0 + wave * 16;

    f4 acc[4];
#pragma unroll
    for (int nt = 0; nt < 4; ++nt) acc[nt] = (f4){0.f, 0.f, 0.f, 0.f};

#pragma unroll
    for (int ks = 0; ks < 2; ++ks) {
        bh8 af = *(const bh8*)(reswb + (size_t)(ocb + col) * 64 + ks * 32 + quad * 8);
#pragma unroll
        for (int nt = 0; nt < 4; ++nt) {
            bh8 bf = *(const bh8*)(tbh + ((size_t)n * L_ATT + l0 + nt * 16 + col) * 64
                                   + ks * 32 + quad * 8);
            acc[nt] = __builtin_amdgcn_mfma_f32_16x16x32_bf16(af, bf, acc[nt], 0, 0, 0);
        }
    }

#pragma unroll
    for (int nt = 0; nt < 4; ++nt) {
        int l = l0 + nt * 16 + col;
#pragma unroll
        for (int reg = 0; reg < 4; ++reg) {
            int oc = ocb + quad * 4 + reg;
            out[((size_t)n * 512 + oc) * L_ATT + l] = acc[nt][reg] + res_b[oc];
        }
    }
}

// ---------------------------------------------------------------------------
extern "C" void kernel_launch(void* const* d_in, const int* in_sizes, int n_in,
                              void* d_out, int out_size, void* d_ws, size_t ws_size,
                              hipStream_t stream)
{
    const float* x      = (const float*)d_in[0];
    const float* qkv_w  = (const float*)d_in[1];
    const float* qkv_b  = (const float*)d_in[2];
    const float* pos_w  = (const float*)d_in[3];
    const float* pos_b  = (const float*)d_in[4];
    const float* res_w  = (const float*)d_in[5];
    const float* res_b  = (const float*)d_in[6];
    float* out = (float*)d_out;

    char* ws = (char*)d_ws;
    short* xt    = (short*)(ws);                    //  9,437,184 B: [4][2304][512]
    short* qkt   = (short*)(ws + 9437184);          //  2,359,296 B: [4][8][2304][16]
    short* vt    = (short*)(ws + 11796480);         //  1,179,648 B: [4][8][8][2304]
    short* tbh   = (short*)(ws + 12976128);         //  1,179,648 B: [4][2304][64]
    short* wqb   = (short*)(ws + 14155776);         //    196,608 B: [192][512]
    short* reswb = (short*)(ws + 14352384);         //     65,536 B: [512][64]
    float* t32   = (float*)d_out;                   // scratch [4][2304][64], overwritten by res

    wcvt_kernel<<<128, 256, 0, stream>>>(qkv_w, res_w, wqb, reswb);
    xt_kernel<<<dim3(36, 8, 4), 256, 0, stream>>>(x, xt);
    qkv_kernel<<<dim3(36, 3, 4), 256, 0, stream>>>(xt, wqb, qkv_b, qkt, vt);
    attn_kernel<<<dim3(36, 8, 4), 256, 0, stream>>>(qkt, vt, t32);
    posconv_kernel<<<dim3(32, 6, 4), 128, 0, stream>>>(vt, pos_w, pos_b, t32, tbh);
    res_kernel<<<dim3(36, 8, 4), 256, 0, stream>>>(tbh, reswb, res_b, out);
}

// Round 4
// 200.253 us; speedup vs baseline: 2.1408x; 1.2330x over previous
//
#include <hip/hip_runtime.h>

#define L_ATT 2304
#define SCALE_ATT 0.35355339059327373f

using bh8 = __attribute__((ext_vector_type(8))) short;  // 8 bf16 (4 VGPRs)
using f4  = __attribute__((ext_vector_type(4))) float;  // 4 fp32 acc

__device__ inline short f2b(float f) {   // RNE
    union { float f; unsigned u; } c; c.f = f;
    unsigned r = (c.u + 0x7FFFu + ((c.u >> 16) & 1u)) >> 16;
    return (short)r;
}
__device__ inline short f2bt(float f) {  // truncate (cheap, for P repack)
    union { float f; unsigned u; } c; c.f = f;
    return (short)(c.u >> 16);
}

// ---------------------------------------------------------------------------
// Weight conversion: qkv_w (192x512) + res_w (512x64) fp32->bf16 natural;
// pos_w (64x64x9) -> wqp[q][oc][ic] bf16. grid 272 x 256.
// ---------------------------------------------------------------------------
__global__ __launch_bounds__(256) void wcvt_kernel(
    const float* __restrict__ qkv_w, const float* __restrict__ res_w,
    const float* __restrict__ pos_w,
    short* __restrict__ wqb, short* __restrict__ reswb, short* __restrict__ wqp)
{
    int j = blockIdx.x * 256 + threadIdx.x;
    if (j < 24576) {
        float4 v = ((const float4*)qkv_w)[j];
        short4 o = { f2b(v.x), f2b(v.y), f2b(v.z), f2b(v.w) };
        *(short4*)(wqb + (size_t)j * 4) = o;
    } else if (j < 32768) {
        int idx = j - 24576;
        float4 v = ((const float4*)res_w)[idx];
        short4 o = { f2b(v.x), f2b(v.y), f2b(v.z), f2b(v.w) };
        *(short4*)(reswb + (size_t)idx * 4) = o;
    } else {
        int e = j - 32768;                 // e = q*4096 + (oc*64+ic)
        wqp[e] = f2b(pos_w[(size_t)(e & 4095) * 9 + (e >> 12)]);
    }
}

// ---------------------------------------------------------------------------
// x [n][512][2304] fp32 -> xt [n][2304][512] bf16 (LDS tile transpose).
// grid (36, 8, 4)
// ---------------------------------------------------------------------------
__global__ __launch_bounds__(256) void xt_kernel(
    const float* __restrict__ x, short* __restrict__ xt)
{
    const int l0 = blockIdx.x * 64, k0 = blockIdx.y * 64, n = blockIdx.z;
    __shared__ float s[64][68];
    const int tr = threadIdx.x >> 4, tc4 = (threadIdx.x & 15) * 4;
    const float* xp = x + ((size_t)n * 512 + k0) * L_ATT + l0;
#pragma unroll
    for (int r = 0; r < 4; ++r)
        *(float4*)&s[tr + r * 16][tc4] =
            *(const float4*)(xp + (size_t)(tr + r * 16) * L_ATT + tc4);
    __syncthreads();
    short* op = xt + ((size_t)n * L_ATT + l0) * 512 + k0;
#pragma unroll
    for (int r = 0; r < 4; ++r) {
        int l = tr + r * 16;
        short4 o = { f2b(s[tc4 + 0][l]), f2b(s[tc4 + 1][l]),
                     f2b(s[tc4 + 2][l]), f2b(s[tc4 + 3][l]) };
        *(short4*)(op + (size_t)l * 512 + tc4) = o;
    }
}

// ---------------------------------------------------------------------------
// qkv 1x1 conv as MFMA GEMM, fragments straight from global.
// Epilogue scatters: q (x SCALE) + k -> qkt[n][h][l][16]; v -> vt[n][h][d][l]
// AND vle[n][l][64] (posconv A-operand layout). grid (36, 3, 4), block 256.
// ---------------------------------------------------------------------------
__global__ __launch_bounds__(256) void qkv_kernel(
    const short* __restrict__ xt, const short* __restrict__ wqb,
    const float* __restrict__ qkv_b, short* __restrict__ qkt,
    short* __restrict__ vt, short* __restrict__ vle)
{
    const int l0 = blockIdx.x * 64, oc0 = blockIdx.y * 64, n = blockIdx.z;
    const int lane = threadIdx.x & 63, wave = threadIdx.x >> 6;
    const int col = lane & 15, quad = lane >> 4;
    const int ocb = oc0 + wave * 16;

    f4 acc[4];
#pragma unroll
    for (int nt = 0; nt < 4; ++nt) acc[nt] = (f4){0.f, 0.f, 0.f, 0.f};

    const short* arow = wqb + (size_t)(ocb + col) * 512 + quad * 8;
    const short* brow = xt + ((size_t)n * L_ATT + l0 + col) * 512 + quad * 8;

#pragma unroll 4
    for (int k0 = 0; k0 < 512; k0 += 32) {
        bh8 af = *(const bh8*)(arow + k0);
        bh8 b0 = *(const bh8*)(brow + k0);
        bh8 b1 = *(const bh8*)(brow + (size_t)16 * 512 + k0);
        bh8 b2 = *(const bh8*)(brow + (size_t)32 * 512 + k0);
        bh8 b3 = *(const bh8*)(brow + (size_t)48 * 512 + k0);
        acc[0] = __builtin_amdgcn_mfma_f32_16x16x32_bf16(af, b0, acc[0], 0, 0, 0);
        acc[1] = __builtin_amdgcn_mfma_f32_16x16x32_bf16(af, b1, acc[1], 0, 0, 0);
        acc[2] = __builtin_amdgcn_mfma_f32_16x16x32_bf16(af, b2, acc[2], 0, 0, 0);
        acc[3] = __builtin_amdgcn_mfma_f32_16x16x32_bf16(af, b3, acc[3], 0, 0, 0);
    }

#pragma unroll
    for (int nt = 0; nt < 4; ++nt) {
        int l = l0 + nt * 16 + col;
#pragma unroll
        for (int reg = 0; reg < 4; ++reg) {
            int oc = ocb + quad * 4 + reg;
            float v = acc[nt][reg] + qkv_b[oc];
            int h = oc / 24;
            int r = oc - h * 24;
            if (r < 16) {
                float sv = (r < 8) ? v * SCALE_ATT : v;
                qkt[(((size_t)(n * 8 + h)) * L_ATT + l) * 16 + r] = f2b(sv);
            } else {
                int d = r - 16;
                short bv = f2b(v);
                vt[(((size_t)(n * 8 + h)) * 8 + d) * L_ATT + l] = bv;
                vle[((size_t)n * L_ATT + l) * 64 + h * 8 + d] = bv;
            }
        }
    }
}

// ---------------------------------------------------------------------------
// Flash attention via MFMA (unchanged structure; cheaper P repack).
// grid (36, 8, 4), block 256.
// ---------------------------------------------------------------------------
__global__ __launch_bounds__(256) void attn_kernel(
    const short* __restrict__ qkt, const short* __restrict__ vt,
    float* __restrict__ t32)
{
    const int q0 = blockIdx.x * 64, h = blockIdx.y, n = blockIdx.z;
    const int lane = threadIdx.x & 63, wave = threadIdx.x >> 6;
    const int col = lane & 15, quad = lane >> 4;

    __shared__ short pbuf[4][16][80];

    const short* qk = qkt + ((size_t)(n * 8 + h)) * L_ATT * 16;
    const short* vb = vt + ((size_t)(n * 8 + h)) * 8 * L_ATT;

    bh8 qf = {0, 0, 0, 0, 0, 0, 0, 0};
    if (quad == 0)
        qf = *(const bh8*)(qk + ((size_t)(q0 + wave * 16 + col)) * 16);

    bh8 onef;
#pragma unroll
    for (int j = 0; j < 8; ++j) onef[j] = (short)0x3F80;  // bf16 1.0

    f4 oacc = (f4){0.f, 0.f, 0.f, 0.f};
    short (*pbw)[80] = pbuf[wave];

    for (int kt = 0; kt < L_ATT; kt += 64) {
        f4 s[4];
#pragma unroll
        for (int nt = 0; nt < 4; ++nt) {
            bh8 kf = {0, 0, 0, 0, 0, 0, 0, 0};
            if (quad == 0)
                kf = *(const bh8*)(qk + ((size_t)(kt + nt * 16 + col)) * 16 + 8);
            f4 z = (f4){0.f, 0.f, 0.f, 0.f};
            s[nt] = __builtin_amdgcn_mfma_f32_16x16x32_bf16(qf, kf, z, 0, 0, 0);
        }
#pragma unroll
        for (int nt = 0; nt < 4; ++nt)
#pragma unroll
            for (int reg = 0; reg < 4; ++reg)
                pbw[quad * 4 + reg][nt * 16 + col] = f2bt(__expf(s[nt][reg]));
        // same-wave LDS RAW: compiler inserts lgkmcnt wait
#pragma unroll
        for (int ks = 0; ks < 2; ++ks) {
            bh8 pf = *(const bh8*)&pbw[col][ks * 32 + quad * 8];
            bh8 vf = {0, 0, 0, 0, 0, 0, 0, 0};
            if (col < 8)
                vf = *(const bh8*)(vb + (size_t)col * L_ATT + kt + ks * 32 + quad * 8);
            else if (col == 8)
                vf = onef;
            oacc = __builtin_amdgcn_mfma_f32_16x16x32_bf16(pf, vf, oacc, 0, 0, 0);
        }
    }

    float outv[4];
#pragma unroll
    for (int reg = 0; reg < 4; ++reg) {
        float ls = __shfl(oacc[reg], (lane & 48) | 8, 64);
        outv[reg] = oacc[reg] / ls;
    }
    if (col < 8) {
#pragma unroll
        for (int reg = 0; reg < 4; ++reg) {
            int l = q0 + wave * 16 + quad * 4 + reg;
            t32[((size_t)n * L_ATT + l) * 64 + h * 8 + col] = outv[reg];
        }
    }
}

// ---------------------------------------------------------------------------
// 3x3 SAME pos-conv as MFMA implicit GEMM: 9 shifted K=64 GEMMs, no LDS.
// D[l][oc] += A_q . B_q^T ; A rows = vle[l+shift][ic] (boundary-masked),
// B rows = wqp[q][oc][ic]. Epilogue: + t32 + bias -> tbh bf16 [l][ch].
// One wave per block, 16 l x 64 oc. grid (144, 4), block 64.
// ---------------------------------------------------------------------------
__global__ __launch_bounds__(64) void posconv_kernel(
    const short* __restrict__ vle, const short* __restrict__ wqp,
    const float* __restrict__ pbias, const float* __restrict__ t32,
    short* __restrict__ tbh)
{
    const int n = blockIdx.y;
    const int lane = threadIdx.x;
    const int l0 = blockIdx.x * 16;
    const int col = lane & 15, quad = lane >> 4;

    const int la = l0 + col;                 // A-row this lane feeds
    const int ya = la / 48, xa = la - ya * 48;

    f4 acc[4];
#pragma unroll
    for (int t = 0; t < 4; ++t) acc[t] = (f4){0.f, 0.f, 0.f, 0.f};

    const short* vbase = vle + (size_t)n * L_ATT * 64;

#pragma unroll
    for (int q = 0; q < 9; ++q) {
        const int dy = q / 3 - 1, dx = q - (q / 3) * 3 - 1;
        const bool valid = ((unsigned)(ya + dy) < 48u) && ((unsigned)(xa + dx) < 48u);
        const short* ap = vbase + (size_t)(la + dy * 48 + dx) * 64 + quad * 8;
#pragma unroll
        for (int ks = 0; ks < 2; ++ks) {
            bh8 af = {0, 0, 0, 0, 0, 0, 0, 0};
            if (valid) af = *(const bh8*)(ap + ks * 32);
#pragma unroll
            for (int t = 0; t < 4; ++t) {
                bh8 bf = *(const bh8*)(wqp + ((size_t)q * 64 + t * 16 + col) * 64
                                       + ks * 32 + quad * 8);
                acc[t] = __builtin_amdgcn_mfma_f32_16x16x32_bf16(af, bf, acc[t], 0, 0, 0);
            }
        }
    }

    const float* tp = t32 + (size_t)n * L_ATT * 64;
    short* op = tbh + (size_t)n * L_ATT * 64;
#pragma unroll
    for (int t = 0; t < 4; ++t) {
        int oc = t * 16 + col;
        float bb = pbias[oc];
#pragma unroll
        for (int reg = 0; reg < 4; ++reg) {
            int l = l0 + quad * 4 + reg;
            size_t idx = (size_t)l * 64 + oc;
            op[idx] = f2b(acc[t][reg] + tp[idx] + bb);
        }
    }
}

// ---------------------------------------------------------------------------
// res 1x1 conv: out[n][oc][l], K=64, fragments direct from global.
// grid (36, 8, 4), block 256.
// ---------------------------------------------------------------------------
__global__ __launch_bounds__(256) void res_kernel(
    const short* __restrict__ tbh, const short* __restrict__ reswb,
    const float* __restrict__ res_b, float* __restrict__ out)
{
    const int l0 = blockIdx.x * 64, oc0 = blockIdx.y * 64, n = blockIdx.z;
    const int lane = threadIdx.x & 63, wave = threadIdx.x >> 6;
    const int col = lane & 15, quad = lane >> 4;
    const int ocb = oc0 + wave * 16;

    f4 acc[4];
#pragma unroll
    for (int nt = 0; nt < 4; ++nt) acc[nt] = (f4){0.f, 0.f, 0.f, 0.f};

#pragma unroll
    for (int ks = 0; ks < 2; ++ks) {
        bh8 af = *(const bh8*)(reswb + (size_t)(ocb + col) * 64 + ks * 32 + quad * 8);
#pragma unroll
        for (int nt = 0; nt < 4; ++nt) {
            bh8 bf = *(const bh8*)(tbh + ((size_t)n * L_ATT + l0 + nt * 16 + col) * 64
                                   + ks * 32 + quad * 8);
            acc[nt] = __builtin_amdgcn_mfma_f32_16x16x32_bf16(af, bf, acc[nt], 0, 0, 0);
        }
    }

#pragma unroll
    for (int nt = 0; nt < 4; ++nt) {
        int l = l0 + nt * 16 + col;
#pragma unroll
        for (int reg = 0; reg < 4; ++reg) {
            int oc = ocb + quad * 4 + reg;
            out[((size_t)n * 512 + oc) * L_ATT + l] = acc[nt][reg] + res_b[oc];
        }
    }
}

// ---------------------------------------------------------------------------
extern "C" void kernel_launch(void* const* d_in, const int* in_sizes, int n_in,
                              void* d_out, int out_size, void* d_ws, size_t ws_size,
                              hipStream_t stream)
{
    const float* x      = (const float*)d_in[0];
    const float* qkv_w  = (const float*)d_in[1];
    const float* qkv_b  = (const float*)d_in[2];
    const float* pos_w  = (const float*)d_in[3];
    const float* pos_b  = (const float*)d_in[4];
    const float* res_w  = (const float*)d_in[5];
    const float* res_b  = (const float*)d_in[6];
    float* out = (float*)d_out;

    char* ws = (char*)d_ws;
    short* xt    = (short*)(ws);                    //  9,437,184 B: [4][2304][512]
    short* qkt   = (short*)(ws + 9437184);          //  2,359,296 B: [4][8][2304][16]
    short* vt    = (short*)(ws + 11796480);         //  1,179,648 B: [4][8][8][2304]
    short* tbh   = (short*)(ws + 12976128);         //  1,179,648 B: [4][2304][64]
    short* wqb   = (short*)(ws + 14155776);         //    196,608 B: [192][512]
    short* reswb = (short*)(ws + 14352384);         //     65,536 B: [512][64]
    short* vle   = (short*)(ws + 14417920);         //  1,179,648 B: [4][2304][64]
    short* wqp   = (short*)(ws + 15597568);         //     73,728 B: [9][64][64]
    float* t32   = (float*)d_out;                   // scratch [4][2304][64] fp32

    wcvt_kernel<<<272, 256, 0, stream>>>(qkv_w, res_w, pos_w, wqb, reswb, wqp);
    xt_kernel<<<dim3(36, 8, 4), 256, 0, stream>>>(x, xt);
    qkv_kernel<<<dim3(36, 3, 4), 256, 0, stream>>>(xt, wqb, qkv_b, qkt, vt, vle);
    attn_kernel<<<dim3(36, 8, 4), 256, 0, stream>>>(qkt, vt, t32);
    posconv_kernel<<<dim3(144, 4), 64, 0, stream>>>(vle, wqp, pos_b, t32, tbh);
    res_kernel<<<dim3(36, 8, 4), 256, 0, stream>>>(tbh, reswb, res_b, out);
}

// Round 5
// 197.618 us; speedup vs baseline: 2.1694x; 1.0133x over previous
//
#include <hip/hip_runtime.h>

#define L_ATT 2304
#define SCALE_ATT 0.35355339059327373f

using bh8 = __attribute__((ext_vector_type(8))) short;  // 8 bf16 (4 VGPRs)
using f4  = __attribute__((ext_vector_type(4))) float;  // 4 fp32 acc

__device__ inline short f2b(float f) {   // RNE
    union { float f; unsigned u; } c; c.f = f;
    unsigned r = (c.u + 0x7FFFu + ((c.u >> 16) & 1u)) >> 16;
    return (short)r;
}
__device__ inline short f2bt(float f) {  // truncate (bias cancels between P and lsum)
    union { float f; unsigned u; } c; c.f = f;
    return (short)(c.u >> 16);
}

// ---------------------------------------------------------------------------
// Weight conversion: qkv_w (192x512) + res_w (512x64) fp32->bf16 natural;
// pos_w (64x64x9) -> wqp[q][oc][ic] bf16. grid 272 x 256.
// ---------------------------------------------------------------------------
__global__ __launch_bounds__(256) void wcvt_kernel(
    const float* __restrict__ qkv_w, const float* __restrict__ res_w,
    const float* __restrict__ pos_w,
    short* __restrict__ wqb, short* __restrict__ reswb, short* __restrict__ wqp)
{
    int j = blockIdx.x * 256 + threadIdx.x;
    if (j < 24576) {
        float4 v = ((const float4*)qkv_w)[j];
        short4 o = { f2b(v.x), f2b(v.y), f2b(v.z), f2b(v.w) };
        *(short4*)(wqb + (size_t)j * 4) = o;
    } else if (j < 32768) {
        int idx = j - 24576;
        float4 v = ((const float4*)res_w)[idx];
        short4 o = { f2b(v.x), f2b(v.y), f2b(v.z), f2b(v.w) };
        *(short4*)(reswb + (size_t)idx * 4) = o;
    } else {
        int e = j - 32768;                 // e = q*4096 + (oc*64+ic)
        wqp[e] = f2b(pos_w[(size_t)(e & 4095) * 9 + (e >> 12)]);
    }
}

// ---------------------------------------------------------------------------
// x [n][512][2304] fp32 -> xt [n][2304][512] bf16 (LDS tile transpose).
// grid (36, 8, 4)
// ---------------------------------------------------------------------------
__global__ __launch_bounds__(256) void xt_kernel(
    const float* __restrict__ x, short* __restrict__ xt)
{
    const int l0 = blockIdx.x * 64, k0 = blockIdx.y * 64, n = blockIdx.z;
    __shared__ float s[64][68];
    const int tr = threadIdx.x >> 4, tc4 = (threadIdx.x & 15) * 4;
    const float* xp = x + ((size_t)n * 512 + k0) * L_ATT + l0;
#pragma unroll
    for (int r = 0; r < 4; ++r)
        *(float4*)&s[tr + r * 16][tc4] =
            *(const float4*)(xp + (size_t)(tr + r * 16) * L_ATT + tc4);
    __syncthreads();
    short* op = xt + ((size_t)n * L_ATT + l0) * 512 + k0;
#pragma unroll
    for (int r = 0; r < 4; ++r) {
        int l = tr + r * 16;
        short4 o = { f2b(s[tc4 + 0][l]), f2b(s[tc4 + 1][l]),
                     f2b(s[tc4 + 2][l]), f2b(s[tc4 + 3][l]) };
        *(short4*)(op + (size_t)l * 512 + tc4) = o;
    }
}

// ---------------------------------------------------------------------------
// qkv 1x1 conv as MFMA GEMM, fragments straight from global.
// Epilogue scatters: q (x SCALE) + k -> qkt[n][h][l][16]; v -> vt[n][h][d][l]
// AND vle[n][l][64] (posconv A-operand layout). grid (36, 3, 4), block 256.
// ---------------------------------------------------------------------------
__global__ __launch_bounds__(256) void qkv_kernel(
    const short* __restrict__ xt, const short* __restrict__ wqb,
    const float* __restrict__ qkv_b, short* __restrict__ qkt,
    short* __restrict__ vt, short* __restrict__ vle)
{
    const int l0 = blockIdx.x * 64, oc0 = blockIdx.y * 64, n = blockIdx.z;
    const int lane = threadIdx.x & 63, wave = threadIdx.x >> 6;
    const int col = lane & 15, quad = lane >> 4;
    const int ocb = oc0 + wave * 16;

    f4 acc[4];
#pragma unroll
    for (int nt = 0; nt < 4; ++nt) acc[nt] = (f4){0.f, 0.f, 0.f, 0.f};

    const short* arow = wqb + (size_t)(ocb + col) * 512 + quad * 8;
    const short* brow = xt + ((size_t)n * L_ATT + l0 + col) * 512 + quad * 8;

#pragma unroll 4
    for (int k0 = 0; k0 < 512; k0 += 32) {
        bh8 af = *(const bh8*)(arow + k0);
        bh8 b0 = *(const bh8*)(brow + k0);
        bh8 b1 = *(const bh8*)(brow + (size_t)16 * 512 + k0);
        bh8 b2 = *(const bh8*)(brow + (size_t)32 * 512 + k0);
        bh8 b3 = *(const bh8*)(brow + (size_t)48 * 512 + k0);
        acc[0] = __builtin_amdgcn_mfma_f32_16x16x32_bf16(af, b0, acc[0], 0, 0, 0);
        acc[1] = __builtin_amdgcn_mfma_f32_16x16x32_bf16(af, b1, acc[1], 0, 0, 0);
        acc[2] = __builtin_amdgcn_mfma_f32_16x16x32_bf16(af, b2, acc[2], 0, 0, 0);
        acc[3] = __builtin_amdgcn_mfma_f32_16x16x32_bf16(af, b3, acc[3], 0, 0, 0);
    }

#pragma unroll
    for (int nt = 0; nt < 4; ++nt) {
        int l = l0 + nt * 16 + col;
#pragma unroll
        for (int reg = 0; reg < 4; ++reg) {
            int oc = ocb + quad * 4 + reg;
            float v = acc[nt][reg] + qkv_b[oc];
            int h = oc / 24;
            int r = oc - h * 24;
            if (r < 16) {
                float sv = (r < 8) ? v * SCALE_ATT : v;
                qkt[(((size_t)(n * 8 + h)) * L_ATT + l) * 16 + r] = f2b(sv);
            } else {
                int d = r - 16;
                short bv = f2b(v);
                vt[(((size_t)(n * 8 + h)) * 8 + d) * L_ATT + l] = bv;
                vle[((size_t)n * L_ATT + l) * 64 + h * 8 + d] = bv;
            }
        }
    }
}

// ---------------------------------------------------------------------------
// Flash attention, ZERO LDS. Per wave: 16 queries.
// S^T = K.Q^T with permuted key mapping key(nt,row)=32*(nt>>1)+8*(row>>2)
// +4*(nt&1)+(row&3), so each lane's 16 exp'd S values are exactly the
// B-fragment (P^T) its PV mfma needs: no cross-lane transform at all.
// PV: O^T = V.P^T; V row d=8 is ones => row 8 of O^T = lsum.
// grid (36, 8, 4), block 256.
// ---------------------------------------------------------------------------
__global__ __launch_bounds__(256) void attn_kernel(
    const short* __restrict__ qkt, const short* __restrict__ vt,
    float* __restrict__ t32)
{
    const int q0 = blockIdx.x * 64, h = blockIdx.y, n = blockIdx.z;
    const int lane = threadIdx.x & 63, wave = threadIdx.x >> 6;
    const int col = lane & 15, quad = lane >> 4;

    const short* qk = qkt + ((size_t)(n * 8 + h)) * L_ATT * 16;
    const short* vb = vt + ((size_t)(n * 8 + h)) * 8 * L_ATT;

    // Q fragment (B operand of S^T mfma): quad 0 holds q[d=0..7] of query col
    bh8 qf = {0, 0, 0, 0, 0, 0, 0, 0};
    if (quad == 0)
        qf = *(const bh8*)(qk + ((size_t)(q0 + wave * 16 + col)) * 16);

    bh8 onef;
#pragma unroll
    for (int j = 0; j < 8; ++j) onef[j] = (short)0x3F80;  // bf16 1.0

    // K fragment pointers: mfma nt reads key = kt + 32*(nt>>1)+4*(nt&1)+koff(col)
    const int koff = 8 * (col >> 2) + (col & 3);
    const short* kp[4];
#pragma unroll
    for (int nt = 0; nt < 4; ++nt)
        kp[nt] = qk + (size_t)(32 * (nt >> 1) + 4 * (nt & 1) + koff) * 16 + 8;

    // V fragment pointers (A operand of PV): lane d=col, keys ks*32+quad*8+j
    const short* vp[2];
#pragma unroll
    for (int ks = 0; ks < 2; ++ks)
        vp[ks] = vb + (size_t)(col & 7) * L_ATT + ks * 32 + quad * 8;

    f4 oacc = (f4){0.f, 0.f, 0.f, 0.f};

    for (int kt = 0; kt < L_ATT; kt += 64) {
        f4 s[4];
#pragma unroll
        for (int nt = 0; nt < 4; ++nt) {
            bh8 kf = {0, 0, 0, 0, 0, 0, 0, 0};
            if (quad == 0)
                kf = *(const bh8*)(kp[nt] + (size_t)kt * 16);
            f4 z = (f4){0.f, 0.f, 0.f, 0.f};
            s[nt] = __builtin_amdgcn_mfma_f32_16x16x32_bf16(kf, qf, z, 0, 0, 0);
        }
        float e[4][4];
#pragma unroll
        for (int nt = 0; nt < 4; ++nt)
#pragma unroll
            for (int reg = 0; reg < 4; ++reg)
                e[nt][reg] = __expf(s[nt][reg]);
#pragma unroll
        for (int ks = 0; ks < 2; ++ks) {
            bh8 pf;
#pragma unroll
            for (int reg = 0; reg < 4; ++reg) {
                pf[reg]     = f2bt(e[2 * ks][reg]);
                pf[reg + 4] = f2bt(e[2 * ks + 1][reg]);
            }
            bh8 vf = {0, 0, 0, 0, 0, 0, 0, 0};
            if (col < 8)      vf = *(const bh8*)(vp[ks] + kt);
            else if (col == 8) vf = onef;
            oacc = __builtin_amdgcn_mfma_f32_16x16x32_bf16(vf, pf, oacc, 0, 0, 0);
        }
    }

    // O^T rows: quad0 -> d0..3, quad1 -> d4..7, quad2/reg0 -> lsum (row 8).
    float ls = __shfl(oacc[0], 32 + col, 64);
    float inv = 1.0f / ls;
    if (quad < 2) {
        int qg = q0 + wave * 16 + col;
        float4 o = { oacc[0] * inv, oacc[1] * inv, oacc[2] * inv, oacc[3] * inv };
        *(float4*)(t32 + ((size_t)n * L_ATT + qg) * 64 + h * 8 + quad * 4) = o;
    }
}

// ---------------------------------------------------------------------------
// 3x3 SAME pos-conv as MFMA implicit GEMM: 9 shifted K=64 GEMMs, no LDS.
// One wave per block, 16 l x 64 oc. grid (144, 4), block 64.
// ---------------------------------------------------------------------------
__global__ __launch_bounds__(64) void posconv_kernel(
    const short* __restrict__ vle, const short* __restrict__ wqp,
    const float* __restrict__ pbias, const float* __restrict__ t32,
    short* __restrict__ tbh)
{
    const int n = blockIdx.y;
    const int lane = threadIdx.x;
    const int l0 = blockIdx.x * 16;
    const int col = lane & 15, quad = lane >> 4;

    const int la = l0 + col;                 // A-row this lane feeds
    const int ya = la / 48, xa = la - ya * 48;

    f4 acc[4];
#pragma unroll
    for (int t = 0; t < 4; ++t) acc[t] = (f4){0.f, 0.f, 0.f, 0.f};

    const short* vbase = vle + (size_t)n * L_ATT * 64;

#pragma unroll
    for (int q = 0; q < 9; ++q) {
        const int dy = q / 3 - 1, dx = q - (q / 3) * 3 - 1;
        const bool valid = ((unsigned)(ya + dy) < 48u) && ((unsigned)(xa + dx) < 48u);
        const short* ap = vbase + (size_t)(la + dy * 48 + dx) * 64 + quad * 8;
#pragma unroll
        for (int ks = 0; ks < 2; ++ks) {
            bh8 af = {0, 0, 0, 0, 0, 0, 0, 0};
            if (valid) af = *(const bh8*)(ap + ks * 32);
#pragma unroll
            for (int t = 0; t < 4; ++t) {
                bh8 bf = *(const bh8*)(wqp + ((size_t)q * 64 + t * 16 + col) * 64
                                       + ks * 32 + quad * 8);
                acc[t] = __builtin_amdgcn_mfma_f32_16x16x32_bf16(af, bf, acc[t], 0, 0, 0);
            }
        }
    }

    const float* tp = t32 + (size_t)n * L_ATT * 64;
    short* op = tbh + (size_t)n * L_ATT * 64;
#pragma unroll
    for (int t = 0; t < 4; ++t) {
        int oc = t * 16 + col;
        float bb = pbias[oc];
#pragma unroll
        for (int reg = 0; reg < 4; ++reg) {
            int l = l0 + quad * 4 + reg;
            size_t idx = (size_t)l * 64 + oc;
            op[idx] = f2b(acc[t][reg] + tp[idx] + bb);
        }
    }
}

// ---------------------------------------------------------------------------
// res 1x1 conv: out[n][oc][l], K=64, fragments direct from global.
// grid (36, 8, 4), block 256.
// ---------------------------------------------------------------------------
__global__ __launch_bounds__(256) void res_kernel(
    const short* __restrict__ tbh, const short* __restrict__ reswb,
    const float* __restrict__ res_b, float* __restrict__ out)
{
    const int l0 = blockIdx.x * 64, oc0 = blockIdx.y * 64, n = blockIdx.z;
    const int lane = threadIdx.x & 63, wave = threadIdx.x >> 6;
    const int col = lane & 15, quad = lane >> 4;
    const int ocb = oc0 + wave * 16;

    f4 acc[4];
#pragma unroll
    for (int nt = 0; nt < 4; ++nt) acc[nt] = (f4){0.f, 0.f, 0.f, 0.f};

#pragma unroll
    for (int ks = 0; ks < 2; ++ks) {
        bh8 af = *(const bh8*)(reswb + (size_t)(ocb + col) * 64 + ks * 32 + quad * 8);
#pragma unroll
        for (int nt = 0; nt < 4; ++nt) {
            bh8 bf = *(const bh8*)(tbh + ((size_t)n * L_ATT + l0 + nt * 16 + col) * 64
                                   + ks * 32 + quad * 8);
            acc[nt] = __builtin_amdgcn_mfma_f32_16x16x32_bf16(af, bf, acc[nt], 0, 0, 0);
        }
    }

#pragma unroll
    for (int nt = 0; nt < 4; ++nt) {
        int l = l0 + nt * 16 + col;
#pragma unroll
        for (int reg = 0; reg < 4; ++reg) {
            int oc = ocb + quad * 4 + reg;
            out[((size_t)n * 512 + oc) * L_ATT + l] = acc[nt][reg] + res_b[oc];
        }
    }
}

// ---------------------------------------------------------------------------
extern "C" void kernel_launch(void* const* d_in, const int* in_sizes, int n_in,
                              void* d_out, int out_size, void* d_ws, size_t ws_size,
                              hipStream_t stream)
{
    const float* x      = (const float*)d_in[0];
    const float* qkv_w  = (const float*)d_in[1];
    const float* qkv_b  = (const float*)d_in[2];
    const float* pos_w  = (const float*)d_in[3];
    const float* pos_b  = (const float*)d_in[4];
    const float* res_w  = (const float*)d_in[5];
    const float* res_b  = (const float*)d_in[6];
    float* out = (float*)d_out;

    char* ws = (char*)d_ws;
    short* xt    = (short*)(ws);                    //  9,437,184 B: [4][2304][512]
    short* qkt   = (short*)(ws + 9437184);          //  2,359,296 B: [4][8][2304][16]
    short* vt    = (short*)(ws + 11796480);         //  1,179,648 B: [4][8][8][2304]
    short* tbh   = (short*)(ws + 12976128);         //  1,179,648 B: [4][2304][64]
    short* wqb   = (short*)(ws + 14155776);         //    196,608 B: [192][512]
    short* reswb = (short*)(ws + 14352384);         //     65,536 B: [512][64]
    short* vle   = (short*)(ws + 14417920);         //  1,179,648 B: [4][2304][64]
    short* wqp   = (short*)(ws + 15597568);         //     73,728 B: [9][64][64]
    float* t32   = (float*)d_out;                   // scratch [4][2304][64] fp32

    wcvt_kernel<<<272, 256, 0, stream>>>(qkv_w, res_w, pos_w, wqb, reswb, wqp);
    xt_kernel<<<dim3(36, 8, 4), 256, 0, stream>>>(x, xt);
    qkv_kernel<<<dim3(36, 3, 4), 256, 0, stream>>>(xt, wqb, qkv_b, qkt, vt, vle);
    attn_kernel<<<dim3(36, 8, 4), 256, 0, stream>>>(qkt, vt, t32);
    posconv_kernel<<<dim3(144, 4), 64, 0, stream>>>(vle, wqp, pos_b, t32, tbh);
    res_kernel<<<dim3(36, 8, 4), 256, 0, stream>>>(tbh, reswb, res_b, out);
}

// Round 6
// 176.569 us; speedup vs baseline: 2.4280x; 1.1192x over previous
//
#include <hip/hip_runtime.h>

#define L_ATT 2304
#define SCALE_ATT 0.35355339059327373f
// SCALE * log2(e): softmax via exp2 is mathematically identical
#define QSCALE_LOG2E 0.5100695712f

using bh8 = __attribute__((ext_vector_type(8))) short;  // 8 bf16 (4 VGPRs)
using f4  = __attribute__((ext_vector_type(4))) float;  // 4 fp32 acc

#if __has_builtin(__builtin_amdgcn_exp2f)
#define EXP2(x) __builtin_amdgcn_exp2f(x)
#else
#define EXP2(x) exp2f(x)
#endif

__device__ inline short f2b(float f) {   // RNE
    union { float f; unsigned u; } c; c.f = f;
    unsigned r = (c.u + 0x7FFFu + ((c.u >> 16) & 1u)) >> 16;
    return (short)r;
}
// pack hi16(lo), hi16(hi) -> one dword (two bf16, truncation; bias cancels in softmax)
__device__ inline int packhi(float lo, float hi) {
    return (int)__builtin_amdgcn_perm(__float_as_uint(hi), __float_as_uint(lo), 0x07060302u);
}

// ---------------------------------------------------------------------------
// Weight conversion: qkv_w (192x512) + res_w (512x64) fp32->bf16 natural;
// pos_w (64x64x9) -> wqp[q][oc][ic] bf16. grid 272 x 256.
// ---------------------------------------------------------------------------
__global__ __launch_bounds__(256) void wcvt_kernel(
    const float* __restrict__ qkv_w, const float* __restrict__ res_w,
    const float* __restrict__ pos_w,
    short* __restrict__ wqb, short* __restrict__ reswb, short* __restrict__ wqp)
{
    int j = blockIdx.x * 256 + threadIdx.x;
    if (j < 24576) {
        float4 v = ((const float4*)qkv_w)[j];
        short4 o = { f2b(v.x), f2b(v.y), f2b(v.z), f2b(v.w) };
        *(short4*)(wqb + (size_t)j * 4) = o;
    } else if (j < 32768) {
        int idx = j - 24576;
        float4 v = ((const float4*)res_w)[idx];
        short4 o = { f2b(v.x), f2b(v.y), f2b(v.z), f2b(v.w) };
        *(short4*)(reswb + (size_t)idx * 4) = o;
    } else {
        int e = j - 32768;                 // e = q*4096 + (oc*64+ic)
        wqp[e] = f2b(pos_w[(size_t)(e & 4095) * 9 + (e >> 12)]);
    }
}

// ---------------------------------------------------------------------------
// x [n][512][2304] fp32 -> xt [n][2304][512] bf16 (LDS tile transpose).
// grid (36, 8, 4)
// ---------------------------------------------------------------------------
__global__ __launch_bounds__(256) void xt_kernel(
    const float* __restrict__ x, short* __restrict__ xt)
{
    const int l0 = blockIdx.x * 64, k0 = blockIdx.y * 64, n = blockIdx.z;
    __shared__ float s[64][68];
    const int tr = threadIdx.x >> 4, tc4 = (threadIdx.x & 15) * 4;
    const float* xp = x + ((size_t)n * 512 + k0) * L_ATT + l0;
#pragma unroll
    for (int r = 0; r < 4; ++r)
        *(float4*)&s[tr + r * 16][tc4] =
            *(const float4*)(xp + (size_t)(tr + r * 16) * L_ATT + tc4);
    __syncthreads();
    short* op = xt + ((size_t)n * L_ATT + l0) * 512 + k0;
#pragma unroll
    for (int r = 0; r < 4; ++r) {
        int l = tr + r * 16;
        short4 o = { f2b(s[tc4 + 0][l]), f2b(s[tc4 + 1][l]),
                     f2b(s[tc4 + 2][l]), f2b(s[tc4 + 3][l]) };
        *(short4*)(op + (size_t)l * 512 + tc4) = o;
    }
}

// ---------------------------------------------------------------------------
// qkv 1x1 conv as MFMA GEMM, fragments straight from global.
// Flat grid 432, XCD-swizzled so the 3 oc-blocks sharing a B-tile (and
// neighbors sharing L2 lines) land on one XCD: code=(l-tile + 36*n), g&7
// constant per code. Epilogue: q (x QSCALE_LOG2E) + k -> qkt; v -> vt + vle.
// ---------------------------------------------------------------------------
__global__ __launch_bounds__(256) void qkv_kernel(
    const short* __restrict__ xt, const short* __restrict__ wqb,
    const float* __restrict__ qkv_b, short* __restrict__ qkt,
    short* __restrict__ vt, short* __restrict__ vle)
{
    const int g = blockIdx.x;              // 432 = 8 * 54
    const int xcd = g & 7, rr = g >> 3;    // rr < 54
    const int y = rr % 3, grp = rr / 3;    // grp < 18
    const int code = grp * 8 + xcd;        // = ltile + 36*n, < 144
    const int l0 = (code % 36) * 64, oc0 = y * 64, n = code / 36;

    const int lane = threadIdx.x & 63, wave = threadIdx.x >> 6;
    const int col = lane & 15, quad = lane >> 4;
    const int ocb = oc0 + wave * 16;

    f4 acc[4];
#pragma unroll
    for (int nt = 0; nt < 4; ++nt) acc[nt] = (f4){0.f, 0.f, 0.f, 0.f};

    const short* arow = wqb + (size_t)(ocb + col) * 512 + quad * 8;
    const short* brow = xt + ((size_t)n * L_ATT + l0 + col) * 512 + quad * 8;

#pragma unroll 4
    for (int k0 = 0; k0 < 512; k0 += 32) {
        bh8 af = *(const bh8*)(arow + k0);
        bh8 b0 = *(const bh8*)(brow + k0);
        bh8 b1 = *(const bh8*)(brow + (size_t)16 * 512 + k0);
        bh8 b2 = *(const bh8*)(brow + (size_t)32 * 512 + k0);
        bh8 b3 = *(const bh8*)(brow + (size_t)48 * 512 + k0);
        acc[0] = __builtin_amdgcn_mfma_f32_16x16x32_bf16(af, b0, acc[0], 0, 0, 0);
        acc[1] = __builtin_amdgcn_mfma_f32_16x16x32_bf16(af, b1, acc[1], 0, 0, 0);
        acc[2] = __builtin_amdgcn_mfma_f32_16x16x32_bf16(af, b2, acc[2], 0, 0, 0);
        acc[3] = __builtin_amdgcn_mfma_f32_16x16x32_bf16(af, b3, acc[3], 0, 0, 0);
    }

#pragma unroll
    for (int nt = 0; nt < 4; ++nt) {
        int l = l0 + nt * 16 + col;
#pragma unroll
        for (int reg = 0; reg < 4; ++reg) {
            int oc = ocb + quad * 4 + reg;
            float v = acc[nt][reg] + qkv_b[oc];
            int h = oc / 24;
            int r = oc - h * 24;
            if (r < 16) {
                float sv = (r < 8) ? v * QSCALE_LOG2E : v;
                qkt[(((size_t)(n * 8 + h)) * L_ATT + l) * 16 + r] = f2b(sv);
            } else {
                int d = r - 16;
                short bv = f2b(v);
                vt[(((size_t)(n * 8 + h)) * 8 + d) * L_ATT + l] = bv;
                vle[((size_t)n * L_ATT + l) * 64 + h * 8 + d] = bv;
            }
        }
    }
}

// ---------------------------------------------------------------------------
// Flash attention, zero LDS, register-double-buffered K/V prefetch.
// Flat grid 1152, XCD-swizzled: h = g&7 so all 36 q-tiles of one (n,h)
// share g%8 -> same XCD -> K/V slice (110 KB) stays L2-hot.
// S^T = K.Q^T with permuted key map; exp2 (q pre-scaled by log2 e);
// P packed via v_perm; PV: O^T = V.P^T, ones-row d=8 gives lsum free.
// ---------------------------------------------------------------------------
__global__ __launch_bounds__(256) void attn_kernel(
    const short* __restrict__ qkt, const short* __restrict__ vt,
    float* __restrict__ t32)
{
    const int g = blockIdx.x;              // 1152 = 8 * 144
    const int h = g & 7, r = g >> 3;       // r < 144
    const int n = r / 36;
    const int q0 = (r % 36) * 64;
    const int lane = threadIdx.x & 63, wave = threadIdx.x >> 6;
    const int col = lane & 15, quad = lane >> 4;

    const short* qk = qkt + ((size_t)(n * 8 + h)) * L_ATT * 16;
    const short* vb = vt + ((size_t)(n * 8 + h)) * 8 * L_ATT;

    bh8 zero8 = {0, 0, 0, 0, 0, 0, 0, 0};
    bh8 qf = zero8;
    if (quad == 0)
        qf = *(const bh8*)(qk + ((size_t)(q0 + wave * 16 + col)) * 16);

    bh8 onef;
#pragma unroll
    for (int j = 0; j < 8; ++j) onef[j] = (short)0x3F80;  // bf16 1.0

    // K fragment pointers: mfma nt reads key = kt + 32*(nt>>1)+4*(nt&1)+koff(col)
    const int koff = 8 * (col >> 2) + (col & 3);
    const short* kp[4];
#pragma unroll
    for (int nt = 0; nt < 4; ++nt)
        kp[nt] = qk + (size_t)(32 * (nt >> 1) + 4 * (nt & 1) + koff) * 16 + 8;

    // V fragment pointers (A operand of PV): row d=col, keys ks*32+quad*8+j
    const short* vp[2];
#pragma unroll
    for (int ks = 0; ks < 2; ++ks)
        vp[ks] = vb + (size_t)(col & 7) * L_ATT + ks * 32 + quad * 8;

    // double-buffered fragments; masked lanes initialized ONCE (stay 0 / ones)
    bh8 kb[2][4], vbuf[2][2];
#pragma unroll
    for (int p = 0; p < 2; ++p) {
#pragma unroll
        for (int nt = 0; nt < 4; ++nt) kb[p][nt] = zero8;
        bh8 vinit = (col == 8) ? onef : zero8;
        vbuf[p][0] = vinit; vbuf[p][1] = vinit;
    }

    // preload tile 0
    if (quad == 0) {
#pragma unroll
        for (int nt = 0; nt < 4; ++nt) kb[0][nt] = *(const bh8*)(kp[nt]);
    }
    if (col < 8) {
#pragma unroll
        for (int ks = 0; ks < 2; ++ks) vbuf[0][ks] = *(const bh8*)(vp[ks]);
    }

    f4 oacc = (f4){0.f, 0.f, 0.f, 0.f};

#pragma unroll 2
    for (int kt = 0; kt < L_ATT; kt += 64) {
        const int p = (kt >> 6) & 1, pn = p ^ 1;
        // prefetch next tile (last iter overruns slice by <2KB — stays inside ws)
        if (quad == 0) {
#pragma unroll
            for (int nt = 0; nt < 4; ++nt)
                kb[pn][nt] = *(const bh8*)(kp[nt] + (size_t)(kt + 64) * 16);
        }
        if (col < 8) {
#pragma unroll
            for (int ks = 0; ks < 2; ++ks)
                vbuf[pn][ks] = *(const bh8*)(vp[ks] + kt + 64);
        }
        // compute on buffer p
        f4 s[4];
#pragma unroll
        for (int nt = 0; nt < 4; ++nt) {
            f4 z = (f4){0.f, 0.f, 0.f, 0.f};
            s[nt] = __builtin_amdgcn_mfma_f32_16x16x32_bf16(kb[p][nt], qf, z, 0, 0, 0);
        }
        float e[4][4];
#pragma unroll
        for (int nt = 0; nt < 4; ++nt)
#pragma unroll
            for (int reg = 0; reg < 4; ++reg)
                e[nt][reg] = EXP2(s[nt][reg]);
#pragma unroll
        for (int ks = 0; ks < 2; ++ks) {
            union { int i[4]; bh8 v; } pu;
            pu.i[0] = packhi(e[2 * ks][0],     e[2 * ks][1]);
            pu.i[1] = packhi(e[2 * ks][2],     e[2 * ks][3]);
            pu.i[2] = packhi(e[2 * ks + 1][0], e[2 * ks + 1][1]);
            pu.i[3] = packhi(e[2 * ks + 1][2], e[2 * ks + 1][3]);
            oacc = __builtin_amdgcn_mfma_f32_16x16x32_bf16(vbuf[p][ks], pu.v, oacc, 0, 0, 0);
        }
    }

    // O^T rows: quad0 -> d0..3, quad1 -> d4..7, quad2/reg0 -> lsum (row 8).
    float ls = __shfl(oacc[0], 32 + col, 64);
    float inv = 1.0f / ls;
    if (quad < 2) {
        int qg = q0 + wave * 16 + col;
        float4 o = { oacc[0] * inv, oacc[1] * inv, oacc[2] * inv, oacc[3] * inv };
        *(float4*)(t32 + ((size_t)n * L_ATT + qg) * 64 + h * 8 + quad * 4) = o;
    }
}

// ---------------------------------------------------------------------------
// 3x3 SAME pos-conv as MFMA implicit GEMM: 9 shifted K=64 GEMMs, no LDS.
// One wave per block, 16 l x 64 oc. grid (144, 4), block 64.
// ---------------------------------------------------------------------------
__global__ __launch_bounds__(64) void posconv_kernel(
    const short* __restrict__ vle, const short* __restrict__ wqp,
    const float* __restrict__ pbias, const float* __restrict__ t32,
    short* __restrict__ tbh)
{
    const int n = blockIdx.y;
    const int lane = threadIdx.x;
    const int l0 = blockIdx.x * 16;
    const int col = lane & 15, quad = lane >> 4;

    const int la = l0 + col;                 // A-row this lane feeds
    const int ya = la / 48, xa = la - ya * 48;

    f4 acc[4];
#pragma unroll
    for (int t = 0; t < 4; ++t) acc[t] = (f4){0.f, 0.f, 0.f, 0.f};

    const short* vbase = vle + (size_t)n * L_ATT * 64;

#pragma unroll
    for (int q = 0; q < 9; ++q) {
        const int dy = q / 3 - 1, dx = q - (q / 3) * 3 - 1;
        const bool valid = ((unsigned)(ya + dy) < 48u) && ((unsigned)(xa + dx) < 48u);
        const short* ap = vbase + (size_t)(la + dy * 48 + dx) * 64 + quad * 8;
#pragma unroll
        for (int ks = 0; ks < 2; ++ks) {
            bh8 af = {0, 0, 0, 0, 0, 0, 0, 0};
            if (valid) af = *(const bh8*)(ap + ks * 32);
#pragma unroll
            for (int t = 0; t < 4; ++t) {
                bh8 bf = *(const bh8*)(wqp + ((size_t)q * 64 + t * 16 + col) * 64
                                       + ks * 32 + quad * 8);
                acc[t] = __builtin_amdgcn_mfma_f32_16x16x32_bf16(af, bf, acc[t], 0, 0, 0);
            }
        }
    }

    const float* tp = t32 + (size_t)n * L_ATT * 64;
    short* op = tbh + (size_t)n * L_ATT * 64;
#pragma unroll
    for (int t = 0; t < 4; ++t) {
        int oc = t * 16 + col;
        float bb = pbias[oc];
#pragma unroll
        for (int reg = 0; reg < 4; ++reg) {
            int l = l0 + quad * 4 + reg;
            size_t idx = (size_t)l * 64 + oc;
            op[idx] = f2b(acc[t][reg] + tp[idx] + bb);
        }
    }
}

// ---------------------------------------------------------------------------
// res 1x1 conv: out[n][oc][l], K=64, fragments direct from global.
// Flat grid 1152, XCD-swizzled: the 8 oc-blocks sharing a tbh B-tile
// (code = ltile + 36*n) share g%8 -> same XCD L2.
// ---------------------------------------------------------------------------
__global__ __launch_bounds__(256) void res_kernel(
    const short* __restrict__ tbh, const short* __restrict__ reswb,
    const float* __restrict__ res_b, float* __restrict__ out)
{
    const int g = blockIdx.x;              // 1152 = 8 * 144
    const int xcd = g & 7, rr = g >> 3;    // rr < 144
    const int y = rr & 7, grp = rr >> 3;   // grp < 18
    const int code = grp * 8 + xcd;        // < 144
    const int l0 = (code % 36) * 64, oc0 = y * 64, n = code / 36;

    const int lane = threadIdx.x & 63, wave = threadIdx.x >> 6;
    const int col = lane & 15, quad = lane >> 4;
    const int ocb = oc0 + wave * 16;

    f4 acc[4];
#pragma unroll
    for (int nt = 0; nt < 4; ++nt) acc[nt] = (f4){0.f, 0.f, 0.f, 0.f};

#pragma unroll
    for (int ks = 0; ks < 2; ++ks) {
        bh8 af = *(const bh8*)(reswb + (size_t)(ocb + col) * 64 + ks * 32 + quad * 8);
#pragma unroll
        for (int nt = 0; nt < 4; ++nt) {
            bh8 bf = *(const bh8*)(tbh + ((size_t)n * L_ATT + l0 + nt * 16 + col) * 64
                                   + ks * 32 + quad * 8);
            acc[nt] = __builtin_amdgcn_mfma_f32_16x16x32_bf16(af, bf, acc[nt], 0, 0, 0);
        }
    }

#pragma unroll
    for (int nt = 0; nt < 4; ++nt) {
        int l = l0 + nt * 16 + col;
#pragma unroll
        for (int reg = 0; reg < 4; ++reg) {
            int oc = ocb + quad * 4 + reg;
            out[((size_t)n * 512 + oc) * L_ATT + l] = acc[nt][reg] + res_b[oc];
        }
    }
}

// ---------------------------------------------------------------------------
extern "C" void kernel_launch(void* const* d_in, const int* in_sizes, int n_in,
                              void* d_out, int out_size, void* d_ws, size_t ws_size,
                              hipStream_t stream)
{
    const float* x      = (const float*)d_in[0];
    const float* qkv_w  = (const float*)d_in[1];
    const float* qkv_b  = (const float*)d_in[2];
    const float* pos_w  = (const float*)d_in[3];
    const float* pos_b  = (const float*)d_in[4];
    const float* res_w  = (const float*)d_in[5];
    const float* res_b  = (const float*)d_in[6];
    float* out = (float*)d_out;

    char* ws = (char*)d_ws;
    short* xt    = (short*)(ws);                    //  9,437,184 B: [4][2304][512]
    short* qkt   = (short*)(ws + 9437184);          //  2,359,296 B: [4][8][2304][16]
    short* vt    = (short*)(ws + 11796480);         //  1,179,648 B: [4][8][8][2304]
    short* tbh   = (short*)(ws + 12976128);         //  1,179,648 B: [4][2304][64]
    short* wqb   = (short*)(ws + 14155776);         //    196,608 B: [192][512]
    short* reswb = (short*)(ws + 14352384);         //     65,536 B: [512][64]
    short* vle   = (short*)(ws + 14417920);         //  1,179,648 B: [4][2304][64]
    short* wqp   = (short*)(ws + 15597568);         //     73,728 B: [9][64][64]
    float* t32   = (float*)d_out;                   // scratch [4][2304][64] fp32

    wcvt_kernel<<<272, 256, 0, stream>>>(qkv_w, res_w, pos_w, wqb, reswb, wqp);
    xt_kernel<<<dim3(36, 8, 4), 256, 0, stream>>>(x, xt);
    qkv_kernel<<<432, 256, 0, stream>>>(xt, wqb, qkv_b, qkt, vt, vle);
    attn_kernel<<<1152, 256, 0, stream>>>(qkt, vt, t32);
    posconv_kernel<<<dim3(144, 4), 64, 0, stream>>>(vle, wqp, pos_b, t32, tbh);
    res_kernel<<<1152, 256, 0, stream>>>(tbh, reswb, res_b, out);
}